// Round 10
// baseline (336.927 us; speedup 1.0000x reference)
//
#include <hip/hip_runtime.h>

#define TLEN 512
#define HID  64

typedef _Float16 half8 __attribute__((ext_vector_type(8)));
typedef float    f32x4 __attribute__((ext_vector_type(4)));

__device__ __forceinline__ float rcp_fast(float x) { return __builtin_amdgcn_rcpf(x); }
__device__ __forceinline__ float exp2_fast(float x) {
#if __has_builtin(__builtin_amdgcn_exp2f)
    return __builtin_amdgcn_exp2f(x);
#else
    float r; asm("v_exp_f32 %0, %1" : "=v"(r) : "v"(x)); return r;
#endif
}

// R10: 256 blocks x 4 waves; block owns 8 batch rows as TWO independent
// groups (A: rows 0-3, B: rows 4-7). Each wave runs BOTH groups' recurrences
// interleaved -> in-wave ILP fills the ~290 cyc/step serial-chain stall that
// R9's two lock-step SMT contexts could not hide (1 act/lane caps the chip at
// 2048 "group-contexts"; R10 packs 2 into one wave instead of 2 waves).
// Per group: R7-validated shape -- 16 cols = 4 real batches x 4 dup, wave w
// owns units [16w,16w+16) as 4 row-permuted A-tiles (shared across groups),
// select-of-4, exactly 1 activation/lane/group. One barrier per step.
// waves_per_eu(1,1): 1 wave/SIMD, 512-reg budget (no AGPR pressure games).
__global__ __launch_bounds__(256) __attribute__((amdgpu_waves_per_eu(1, 1)))
void lstm_mfma7(const float* __restrict__ x,
                const float* __restrict__ W_ih,
                const float* __restrict__ W_hh,
                const float* __restrict__ b_ih,
                const float* __restrict__ b_hh,
                const float* __restrict__ W_d,
                const float* __restrict__ b_d,
                float* __restrict__ out) {
    __shared__ __align__(16) float    xs[8][516];    // 8 x rows
    __shared__ __align__(16) _Float16 ha[2][4][72];  // group A h ping-pong
    __shared__ __align__(16) _Float16 hb[2][4][72];  // group B h ping-pong

    const int tid = threadIdx.x;
    const int L   = tid & 63;
    const int w   = tid >> 6;        // wave 0..3, owns units [16w, 16w+16)
    const int r0  = blockIdx.x * 8;

    // ---- stage x rows (float4) ----
    for (int i = tid; i < 8 * 128; i += 256) {
        const int r = i >> 7, t4 = (i & 127) * 4;
        *(float4*)&xs[r][t4] = *(const float4*)&x[(size_t)(r0 + r) * TLEN + t4];
    }
    // ---- zero all h buffers (h0 = 0) ----
    for (int i = tid; i < 2 * 4 * 72; i += 256) {
        ((_Float16*)ha)[i] = (_Float16)0.0f;
        ((_Float16*)hb)[i] = (_Float16)0.0f;
    }

    // ---- resident A-frags (shared by both groups): A[m][k], m=L&15 ----
    // perm: tile tt -> unit 16w+4tt+(m>>2), gate m&3 (i,f,g,o)
    half8 af[4][2];
    {
        const int m = L & 15;
        const int g = m & 3;
        const int kb = (L >> 4) * 8;
#pragma unroll
        for (int tt = 0; tt < 4; ++tt) {
            const int uu = 16 * w + 4 * tt + (m >> 2);
            const float* row = &W_hh[(size_t)(g * HID + uu) * HID];
#pragma unroll
            for (int q = 0; q < 2; ++q) {
                const float* p = row + 32 * q + kb;
                half8 hf;
#pragma unroll
                for (int i = 0; i < 8; ++i) hf[i] = (_Float16)p[i];
                af[tt][q] = hf;
            }
        }
    }

    // ---- lane role (same (b4,u) for both groups): 64 unique pairs/wave ----
    const int c   = L & 15;
    const int b4  = c & 3;           // real batch within group
    const int sel = (c >> 2) & 3;    // dup group -> tile select
    const int u   = 16 * w + 4 * sel + (L >> 4);

    const float K = 1.44269504f;
    float wih[4], bias[4], dscl[4];
#pragma unroll
    for (int g = 0; g < 4; ++g) {
        const float s = (g == 2) ? 2.0f * K : -K;  // tanh gate +2K, sigmoid -K
        wih[g]  = s * W_ih[g * HID + u];
        bias[g] = s * (b_ih[g * HID + u] + b_hh[g * HID + u]);
        dscl[g] = s;
    }

    const float* xrA = &xs[b4][0];
    const float* xrB = &xs[b4 + 4][0];
    const int koff = (L >> 4) * 8;
    const f32x4 zero = {0.0f, 0.0f, 0.0f, 0.0f};
    float cA = 0.0f, cB = 0.0f;

    __syncthreads();

    auto act = [&](const f32x4& d, float xt, float& cst) -> _Float16 {
        const float ei = exp2_fast(fmaf(d[0], dscl[0], fmaf(xt, wih[0], bias[0])));
        const float ef = exp2_fast(fmaf(d[1], dscl[1], fmaf(xt, wih[1], bias[1])));
        const float eg = exp2_fast(fmaf(d[2], dscl[2], fmaf(xt, wih[2], bias[2])));
        const float eo = exp2_fast(fmaf(d[3], dscl[3], fmaf(xt, wih[3], bias[3])));
        const float gi = rcp_fast(1.0f + ei);
        const float gf = rcp_fast(1.0f + ef);
        const float gg = fmaf(-2.0f, rcp_fast(1.0f + eg), 1.0f);
        const float go = rcp_fast(1.0f + eo);
        cst = fmaf(gf, cst, gi * gg);
        const float tc = fmaf(-2.0f, rcp_fast(1.0f + exp2_fast(2.0f * K * cst)), 1.0f);
        return (_Float16)(go * tc);
    };

    auto step = [&](int p, float xtA, float xtB) {
        // both groups' B-frags issued back-to-back: 4 independent ds_read_b128
        const _Float16* hA = &ha[p][b4][koff];
        const _Float16* hB = &hb[p][b4][koff];
        half8 a0 = *(const half8*)hA;
        half8 a1 = *(const half8*)(hA + 32);
        half8 g0 = *(const half8*)hB;
        half8 g1 = *(const half8*)(hB + 32);

        f32x4 dA0 = __builtin_amdgcn_mfma_f32_16x16x32_f16(af[0][0], a0, zero, 0, 0, 0);
        f32x4 dA1 = __builtin_amdgcn_mfma_f32_16x16x32_f16(af[1][0], a0, zero, 0, 0, 0);
        f32x4 dA2 = __builtin_amdgcn_mfma_f32_16x16x32_f16(af[2][0], a0, zero, 0, 0, 0);
        f32x4 dA3 = __builtin_amdgcn_mfma_f32_16x16x32_f16(af[3][0], a0, zero, 0, 0, 0);
        f32x4 dB0 = __builtin_amdgcn_mfma_f32_16x16x32_f16(af[0][0], g0, zero, 0, 0, 0);
        f32x4 dB1 = __builtin_amdgcn_mfma_f32_16x16x32_f16(af[1][0], g0, zero, 0, 0, 0);
        f32x4 dB2 = __builtin_amdgcn_mfma_f32_16x16x32_f16(af[2][0], g0, zero, 0, 0, 0);
        f32x4 dB3 = __builtin_amdgcn_mfma_f32_16x16x32_f16(af[3][0], g0, zero, 0, 0, 0);
        dA0 = __builtin_amdgcn_mfma_f32_16x16x32_f16(af[0][1], a1, dA0, 0, 0, 0);
        dA1 = __builtin_amdgcn_mfma_f32_16x16x32_f16(af[1][1], a1, dA1, 0, 0, 0);
        dA2 = __builtin_amdgcn_mfma_f32_16x16x32_f16(af[2][1], a1, dA2, 0, 0, 0);
        dA3 = __builtin_amdgcn_mfma_f32_16x16x32_f16(af[3][1], a1, dA3, 0, 0, 0);
        dB0 = __builtin_amdgcn_mfma_f32_16x16x32_f16(af[0][1], g1, dB0, 0, 0, 0);
        dB1 = __builtin_amdgcn_mfma_f32_16x16x32_f16(af[1][1], g1, dB1, 0, 0, 0);
        dB2 = __builtin_amdgcn_mfma_f32_16x16x32_f16(af[2][1], g1, dB2, 0, 0, 0);
        dB3 = __builtin_amdgcn_mfma_f32_16x16x32_f16(af[3][1], g1, dB3, 0, 0, 0);

        const f32x4 dA = sel == 0 ? dA0 : (sel == 1 ? dA1 : (sel == 2 ? dA2 : dA3));
        const f32x4 dB = sel == 0 ? dB0 : (sel == 1 ? dB1 : (sel == 2 ? dB2 : dB3));

        // two independent activation chains: B's issue fills A's stalls
        const _Float16 hvA = act(dA, xtA, cA);
        const _Float16 hvB = act(dB, xtB, cB);
        ha[p ^ 1][b4][u] = hvA;
        hb[p ^ 1][b4][u] = hvB;
        __syncthreads();
    };

    for (int t = 0; t < TLEN; t += 2) {
        step(0, xrA[t],     xrB[t]);
        step(1, xrA[t + 1], xrB[t + 1]);
    }

    // ---- epilogue: wave w reduces group-A row w and group-B row w ----
    float pv = (float)ha[0][w][L] * W_d[L];
#pragma unroll
    for (int off = 32; off > 0; off >>= 1)
        pv += __shfl_xor(pv, off, 64);
    if (L == 0) out[r0 + w] = pv + b_d[0];

    float pw = (float)hb[0][w][L] * W_d[L];
#pragma unroll
    for (int off = 32; off > 0; off >>= 1)
        pw += __shfl_xor(pw, off, 64);
    if (L == 0) out[r0 + 4 + w] = pw + b_d[0];
}

extern "C" void kernel_launch(void* const* d_in, const int* in_sizes, int n_in,
                              void* d_out, int out_size, void* d_ws, size_t ws_size,
                              hipStream_t stream) {
    const float* x    = (const float*)d_in[0];
    const float* W_ih = (const float*)d_in[1];
    const float* W_hh = (const float*)d_in[2];
    const float* b_ih = (const float*)d_in[3];
    const float* b_hh = (const float*)d_in[4];
    const float* W_d  = (const float*)d_in[5];
    const float* b_d  = (const float*)d_in[6];
    float* out = (float*)d_out;

    dim3 grid(256);    // 8 batch rows per block (two groups of 4)
    dim3 block(256);   // 4 waves = 1 wave/SIMD, 2 recurrences in-wave
    lstm_mfma7<<<grid, block, 0, stream>>>(x, W_ih, W_hh, b_ih, b_hh, W_d, b_d, out);
}

// Round 11
// 212.594 us; speedup vs baseline: 1.5848x; 1.5848x over previous
//
#include <hip/hip_runtime.h>

#define TLEN 512
#define HID  64

typedef _Float16 half8 __attribute__((ext_vector_type(8)));
typedef float    f32x4 __attribute__((ext_vector_type(4)));

__device__ __forceinline__ float rcp_fast(float x) { return __builtin_amdgcn_rcpf(x); }
__device__ __forceinline__ float exp2_fast(float x) {
#if __has_builtin(__builtin_amdgcn_exp2f)
    return __builtin_amdgcn_exp2f(x);
#else
    float r; asm("v_exp_f32 %0, %1" : "=v"(r) : "v"(x)); return r;
#endif
}

// R11 = R9 (best: 176 us) + micro-cuts. Shape: 256 blocks x 8 waves, block
// owns 8 real batch rows (16 MFMA cols = 8 real x 2 dup), wave owns 8 units
// as 2 row-permuted A-tiles, exactly 1 activation/lane (census invariant:
// chip act issue ~240 cyc/SIMD-step at 1 act/lane; 2 waves/SIMD > 1 [R10]).
// Cuts vs R9:
//  1. K-split partial MFMAs: 4 independent mfma into zero-acc, VALU-summed;
//     removes chained-MFMA latency (~30 cyc) from the per-step critical path.
//  2. x register-blocking: one b128 read / 4 steps (was 4x b32) -- trims the
//     post-barrier LDS-pipe burst (~190 cyc/CU-step, the main dead-time).
//  3. pre-gate fma issued before MFMA results are needed.
__global__ __launch_bounds__(512) __attribute__((amdgpu_waves_per_eu(2, 2)))
void lstm_mfma8(const float* __restrict__ x,
                const float* __restrict__ W_ih,
                const float* __restrict__ W_hh,
                const float* __restrict__ b_ih,
                const float* __restrict__ b_hh,
                const float* __restrict__ W_d,
                const float* __restrict__ b_d,
                float* __restrict__ out) {
    __shared__ __align__(16) float    xs[8][516];     // 8 x rows
    __shared__ __align__(16) _Float16 hbuf[2][8][72]; // ping-pong h

    const int tid = threadIdx.x;
    const int L   = tid & 63;
    const int w   = tid >> 6;        // wave 0..7, owns units [8w, 8w+8)
    const int r0  = blockIdx.x * 8;

    // ---- stage x rows (float4) ----
    for (int i = tid; i < 8 * 128; i += 512) {
        const int r = i >> 7, t4 = (i & 127) * 4;
        *(float4*)&xs[r][t4] = *(const float4*)&x[(size_t)(r0 + r) * TLEN + t4];
    }
    // ---- zero both h buffers (h0 = 0) ----
    for (int i = tid; i < 2 * 8 * 72; i += 512)
        ((_Float16*)hbuf)[i] = (_Float16)0.0f;

    // ---- resident A-frags: A[m][k], m=L&15, k=32q+(L>>4)*8+i ----
    // perm: tile tt -> unit 8w+4tt+(m>>2), gate m&3 (i,f,g,o)
    half8 af[2][2];
    {
        const int m = L & 15;
        const int g = m & 3;
        const int kb = (L >> 4) * 8;
#pragma unroll
        for (int tt = 0; tt < 2; ++tt) {
            const int uu = 8 * w + 4 * tt + (m >> 2);
            const float* row = &W_hh[(size_t)(g * HID + uu) * HID];
#pragma unroll
            for (int q = 0; q < 2; ++q) {
                const float* p = row + 32 * q + kb;
                half8 hf;
#pragma unroll
                for (int i = 0; i < 8; ++i) hf[i] = (_Float16)p[i];
                af[tt][q] = hf;
            }
        }
    }

    // ---- lane role: col c, batch b (8 real rows), tile-select dup, unit u ----
    const int c   = L & 15;
    const int b   = c & 7;
    const int dup = (c >> 3) & 1;
    const int u   = 8 * w + 4 * dup + (L >> 4);
    // 64 lanes <-> 64 distinct (b,u): exactly one activation per lane.

    // exp2-domain gate params: sigmoid arg -K*a, tanh arg +2K*a (K=log2 e)
    const float K = 1.44269504f;
    float wih[4], bias[4], dscl[4];
#pragma unroll
    for (int g = 0; g < 4; ++g) {
        const float s = (g == 2) ? 2.0f * K : -K;
        wih[g]  = s * W_ih[g * HID + u];
        bias[g] = s * (b_ih[g * HID + u] + b_hh[g * HID + u]);
        dscl[g] = s;
    }

    const float* xrow = &xs[b][0];
    const int koff = (L >> 4) * 8;
    const _Float16* h0r = &hbuf[0][b][0];
    _Float16*       h0w = &hbuf[0][0][0];
    const _Float16* h1r = &hbuf[1][b][0];
    _Float16*       h1w = &hbuf[1][0][0];
    const int widx = b * 72 + u;     // write offset within a buffer
    const f32x4 zero = {0.0f, 0.0f, 0.0f, 0.0f};
    float cst = 0.0f;

    __syncthreads();

    auto step = [&](const _Float16* hin, _Float16* hout, float xt) {
        // pre-gates: ready before MFMA results are consumed
        const float pre0 = fmaf(xt, wih[0], bias[0]);
        const float pre1 = fmaf(xt, wih[1], bias[1]);
        const float pre2 = fmaf(xt, wih[2], bias[2]);
        const float pre3 = fmaf(xt, wih[3], bias[3]);

        half8 b0 = *(const half8*)(hin + koff);
        half8 b1 = *(const half8*)(hin + koff + 32);

        // K-split partials: 4 independent MFMAs (no acc chaining)
        f32x4 p0 = __builtin_amdgcn_mfma_f32_16x16x32_f16(af[0][0], b0, zero, 0, 0, 0);
        f32x4 p1 = __builtin_amdgcn_mfma_f32_16x16x32_f16(af[1][0], b0, zero, 0, 0, 0);
        f32x4 q0 = __builtin_amdgcn_mfma_f32_16x16x32_f16(af[0][1], b1, zero, 0, 0, 0);
        f32x4 q1 = __builtin_amdgcn_mfma_f32_16x16x32_f16(af[1][1], b1, zero, 0, 0, 0);

        const f32x4 dP = dup ? p1 : p0;   // 4 cndmask each
        const f32x4 dQ = dup ? q1 : q0;

        const float ei = exp2_fast(fmaf(dP[0] + dQ[0], dscl[0], pre0));
        const float ef = exp2_fast(fmaf(dP[1] + dQ[1], dscl[1], pre1));
        const float eg = exp2_fast(fmaf(dP[2] + dQ[2], dscl[2], pre2));
        const float eo = exp2_fast(fmaf(dP[3] + dQ[3], dscl[3], pre3));
        const float gi = rcp_fast(1.0f + ei);                    // sigmoid(i)
        const float gf = rcp_fast(1.0f + ef);                    // sigmoid(f)
        const float gg = fmaf(-2.0f, rcp_fast(1.0f + eg), 1.0f); // tanh(g)
        const float go = rcp_fast(1.0f + eo);                    // sigmoid(o)
        cst = fmaf(gf, cst, gi * gg);
        const float tc = fmaf(-2.0f, rcp_fast(1.0f + exp2_fast(2.0f * K * cst)), 1.0f);
        hout[widx] = (_Float16)(go * tc);  // one write per lane, 64 unique (b,u)
    };

    for (int t = 0; t < TLEN; t += 4) {
        // x register-blocking: one b128 read covers 4 steps (16B-aligned)
        const float4 xq = *(const float4*)&xrow[t];
        step(h0r, h1w, xq.x);
        __syncthreads();
        step(h1r, h0w, xq.y);
        __syncthreads();
        step(h0r, h1w, xq.z);
        __syncthreads();
        step(h1r, h0w, xq.w);
        __syncthreads();
    }

    // ---- epilogue: wave w reduces batch row w (final h in hbuf[0]) ----
    float pv = (float)hbuf[0][w][L] * W_d[L];
#pragma unroll
    for (int off = 32; off > 0; off >>= 1)
        pv += __shfl_xor(pv, off, 64);
    if (L == 0)
        out[r0 + w] = pv + b_d[0];
}

extern "C" void kernel_launch(void* const* d_in, const int* in_sizes, int n_in,
                              void* d_out, int out_size, void* d_ws, size_t ws_size,
                              hipStream_t stream) {
    const float* x    = (const float*)d_in[0];
    const float* W_ih = (const float*)d_in[1];
    const float* W_hh = (const float*)d_in[2];
    const float* b_ih = (const float*)d_in[3];
    const float* b_hh = (const float*)d_in[4];
    const float* W_d  = (const float*)d_in[5];
    const float* b_d  = (const float*)d_in[6];
    float* out = (float*)d_out;

    dim3 grid(256);    // 2048 / 8 batch rows per block
    dim3 block(512);   // 8 waves = 2/SIMD (1-act/lane occupancy floor)
    lstm_mfma8<<<grid, block, 0, stream>>>(x, W_ih, W_hh, b_ih, b_hh, W_d, b_d, out);
}